// Round 5
// baseline (63408.624 us; speedup 1.0000x reference)
//
#include <hip/hip_runtime.h>
#include <cstdint>

#define T_STEPS 8192
#define HDIM    768
#define G3      2304   // 3*H
#define NDR     4608   // 2*3*H
#define HC      1536   // 2*H
#define GPD     24     // workgroups per direction
#define NWG     48     // 2 dirs x 24 WGs (independent cliques)
#define C_ROWS  32     // h-rows per workgroup (2 per wave, 16 waves)

// ---------------------------------------------------------------------------
// GEMM: C[m][n] = sum_k X[m][k] * W[n][k] + bias[n]  (unchanged)
// ---------------------------------------------------------------------------
__global__ __launch_bounds__(256)
void gemm_xwt(const float* __restrict__ X, const float* __restrict__ W,
              const float* __restrict__ bias, float* __restrict__ C,
              int M, int N, int K) {
    __shared__ float As[16][132];
    __shared__ float Bs[16][132];
    const int tid = threadIdx.x;
    const int m0 = blockIdx.y * 128;
    const int n0 = blockIdx.x * 128;
    const int tm = tid >> 4;
    const int tn = tid & 15;
    float acc[8][8] = {};
    for (int k0 = 0; k0 < K; k0 += 16) {
        #pragma unroll
        for (int l = 0; l < 2; ++l) {
            int idx = l * 256 + tid;
            int row = idx >> 2;
            int kc  = (idx & 3) << 2;
            float4 a = *(const float4*)(X + (size_t)(m0 + row) * K + k0 + kc);
            As[kc + 0][row] = a.x; As[kc + 1][row] = a.y;
            As[kc + 2][row] = a.z; As[kc + 3][row] = a.w;
            float4 b = *(const float4*)(W + (size_t)(n0 + row) * K + k0 + kc);
            Bs[kc + 0][row] = b.x; Bs[kc + 1][row] = b.y;
            Bs[kc + 2][row] = b.z; Bs[kc + 3][row] = b.w;
        }
        __syncthreads();
        #pragma unroll
        for (int k = 0; k < 16; ++k) {
            float4 a0 = *(const float4*)&As[k][tm * 8];
            float4 a1 = *(const float4*)&As[k][tm * 8 + 4];
            float4 b0 = *(const float4*)&Bs[k][tn * 8];
            float4 b1 = *(const float4*)&Bs[k][tn * 8 + 4];
            float av[8] = {a0.x, a0.y, a0.z, a0.w, a1.x, a1.y, a1.z, a1.w};
            float bv[8] = {b0.x, b0.y, b0.z, b0.w, b1.x, b1.y, b1.z, b1.w};
            #pragma unroll
            for (int i = 0; i < 8; ++i)
                #pragma unroll
                for (int j = 0; j < 8; ++j)
                    acc[i][j] = fmaf(av[i], bv[j], acc[i][j]);
        }
        __syncthreads();
    }
    float bfrag[8];
    #pragma unroll
    for (int j = 0; j < 8; ++j) bfrag[j] = bias[n0 + tn * 8 + j];
    #pragma unroll
    for (int i = 0; i < 8; ++i) {
        float* cp = C + (size_t)(m0 + tm * 8 + i) * N + n0 + tn * 8;
        float4 o0, o1;
        o0.x = acc[i][0] + bfrag[0]; o0.y = acc[i][1] + bfrag[1];
        o0.z = acc[i][2] + bfrag[2]; o0.w = acc[i][3] + bfrag[3];
        o1.x = acc[i][4] + bfrag[4]; o1.y = acc[i][5] + bfrag[5];
        o1.z = acc[i][6] + bfrag[6]; o1.w = acc[i][7] + bfrag[7];
        *(float4*)(cp + 0) = o0;
        *(float4*)(cp + 4) = o1;
    }
}

// ---------------------------------------------------------------------------
// GRU recurrence, R14: 24 WGs/dir x 1024 thr (16 waves, 2 rows/wave).
// vs R13 (96 WGs x 256, 18.0 ms): same per-wave compute (6 dots of 768,
// same dot partition, same 6-stage butterfly -> bit-identical sums), but:
// 1) PER-WAVE GATES: after the butterfly every lane holds all 6 sums, so
//    lanes 0-1 of each wave compute their own rows' gates and publish
//    directly. Removes from the chain: gsum LDS round-trip, barrier#2,
//    wave-0 8-row serialized gates (~600-900 cy/step).
// 2) ONE barrier/step. hsh is parity-double-buffered; a wave can lead its
//    WG-mates by at most 1 step (the next barrier requires everyone), and
//    poll(s) writes hsh[s&1] while a 1-step-behind wave reads hsh[(s-1)&1]
//    -> no conflict.
// 3) PER-LANE SPIN: threads 0..767 each poll exactly one pair (wave-load =
//    8 consecutive lines); failing lanes re-load under exec mask ->
//    minimal traffic, finest-grained detection. 24 consumers/dir instead
//    of 96 -> 4x fewer poll requests and 4x fewer jitter sources in the
//    per-step max().
// Protocol unchanged (tags, 2-deep parity, agent scope for all exch ops).
// Cross-WG overwrite safety: slot holding tag u (parity (u-1)&1) is
// overwritten at step u+1 by producer P. P publishes(u+1) only after P's
// poll(u+1) saw tag u+1 on ALL rows; tag u+1 is published by each consumer
// C at step u AFTER C's barrier(u), which requires every poll lane of C
// (including the one reading our slot) to have read tag >= u. Read happens
// before overwrite. Same induction as R9/R13.
// ---------------------------------------------------------------------------
__device__ __forceinline__ float sigf(float x) {
    return 1.0f / (1.0f + expf(-x));
}
__device__ __forceinline__ unsigned long long ld_pair(
        const unsigned long long* p) {
    return __hip_atomic_load(p, __ATOMIC_RELAXED, __HIP_MEMORY_SCOPE_AGENT);
}
__device__ __forceinline__ void st_pair(unsigned long long* p,
                                        unsigned long long v) {
    __hip_atomic_store(p, v, __ATOMIC_RELAXED, __HIP_MEMORY_SCOPE_AGENT);
}

__global__ __launch_bounds__(1024, 1)
void gru_rec(const float* __restrict__ Gi,   // [T][2][2304]
             const float* __restrict__ whh,  // [2][2304][768]
             const float* __restrict__ bhh,  // [2][2304]
             const float* __restrict__ h0,   // [2][768] (layer slice)
             unsigned long long* __restrict__ exch, // [2 par][2 dir][768]
             float* __restrict__ Hout) {     // [T][2][768]
    const int tid  = threadIdx.x;
    const int lane = tid & 63;
    const int wave = tid >> 6;
    const int bid  = blockIdx.x;
    const int d    = bid / GPD;
    const int j0   = (bid % GPD) * C_ROWS;
    const int row2 = j0 + 2 * wave;          // first of this wave's two rows

    __shared__ float hsh[2][768];

    // Register-resident weights: m = g*2 + ri -> gate g, row = row2 + ri.
    // w[m][i] covers h elements i*256 + lane*4 .. +3 (same partition as R13).
    float4 w[6][3];
    #pragma unroll
    for (int g = 0; g < 3; ++g)
        #pragma unroll
        for (int ri = 0; ri < 2; ++ri) {
            const float* wrow = whh + (size_t)d * G3 * HDIM
                + (size_t)(g * 768 + row2 + ri) * HDIM;
            #pragma unroll
            for (int i = 0; i < 3; ++i)
                w[g * 2 + ri][i] = *(const float4*)(wrow + i * 256 + lane * 4);
        }

    // Gate lanes (lane 0-1 of every wave): row = row2 + lane.
    float bh_r = 0.f, bh_z = 0.f, bh_n = 0.f, hprev = 0.f;
    float gi_r = 0.f, gi_z = 0.f, gi_n = 0.f;
    if (lane < 2) {
        const int row = row2 + lane;
        bh_r  = bhh[d * G3 +        row];
        bh_z  = bhh[d * G3 +  768 + row];
        bh_n  = bhh[d * G3 + 1536 + row];
        hprev = h0[d * 768 + row];
        const float* gp = Gi + (size_t)d * G3;      // t = 0
        gi_r = gp[        row];
        gi_z = gp[ 768 + row];
        gi_n = gp[1536 + row];
    }

    for (int t = 0; t < T_STEPS; ++t) {
        // --- Phase 1: per-lane spin poll (threads 0..767, one pair each) ---
        if (tid < 768) {
            if (t == 0) {
                hsh[0][tid] = h0[d * 768 + tid];
            } else {
                const unsigned long long* src = exch
                    + (size_t)((((t - 1) & 1) * 2 + d)) * 768 + tid;
                unsigned long long v;
                do { v = ld_pair(src); } while ((unsigned)v < (unsigned)t);
                hsh[t & 1][tid] = __uint_as_float((unsigned)(v >> 32));
            }
        }
        __syncthreads();

        // --- Phase 2: deferred Hout(t-1) + Gi prefetch(t+1) (gate lanes) ---
        float ngr = 0.f, ngz = 0.f, ngn = 0.f;
        if (lane < 2) {
            const int row = row2 + lane;
            if (t > 0)
                Hout[((size_t)(t - 1) * 2 + d) * 768 + row] = hprev;
            if (t + 1 < T_STEPS) {
                const float* gp = Gi + ((size_t)(t + 1) * 2 + d) * G3;
                ngr = gp[        row];
                ngz = gp[ 768 + row];
                ngn = gp[1536 + row];
            }
        }

        // --- dots + butterfly (identical arithmetic to R13) ---
        const float* hb = hsh[t & 1];
        float4 h4[3];
        #pragma unroll
        for (int i = 0; i < 3; ++i)
            h4[i] = *(const float4*)&hb[i * 256 + lane * 4];

        float S[6];
        #pragma unroll
        for (int m = 0; m < 6; ++m) {
            float s = 0.f;
            s = fmaf(w[m][0].x, h4[0].x, s); s = fmaf(w[m][0].y, h4[0].y, s);
            s = fmaf(w[m][0].z, h4[0].z, s); s = fmaf(w[m][0].w, h4[0].w, s);
            s = fmaf(w[m][1].x, h4[1].x, s); s = fmaf(w[m][1].y, h4[1].y, s);
            s = fmaf(w[m][1].z, h4[1].z, s); s = fmaf(w[m][1].w, h4[1].w, s);
            s = fmaf(w[m][2].x, h4[2].x, s); s = fmaf(w[m][2].y, h4[2].y, s);
            s = fmaf(w[m][2].z, h4[2].z, s); s = fmaf(w[m][2].w, h4[2].w, s);
            S[m] = s;
        }
        #pragma unroll
        for (int sft = 1; sft < 64; sft <<= 1) {
            #pragma unroll
            for (int m = 0; m < 6; ++m) S[m] += __shfl_xor(S[m], sft);
        }

        // --- Phase 3: per-wave gates + immediate publish (lanes 0-1) ---
        if (lane < 2) {
            float Sr = lane ? S[1] : S[0];
            float Sz = lane ? S[3] : S[2];
            float Sn = lane ? S[5] : S[4];
            float r = sigf(gi_r + Sr + bh_r);
            float z = sigf(gi_z + Sz + bh_z);
            float n = tanhf(gi_n + r * (Sn + bh_n));
            float hn = (1.0f - z) * n + z * hprev;
            hprev = hn;
            unsigned long long pair =
                ((unsigned long long)__float_as_uint(hn) << 32)
                | (unsigned long long)(unsigned)(t + 1);
            st_pair(exch + (size_t)(((t & 1) * 2 + d)) * 768 + row2 + lane,
                    pair);
            gi_r = ngr; gi_z = ngz; gi_n = ngn;
        }
        // single barrier per step: next iteration's phase-1 barrier orders
        // everything; hsh parity covers the <=1-step intra-WG skew.
    }
    // flush the last Hout row
    if (lane < 2)
        Hout[((size_t)(T_STEPS - 1) * 2 + d) * 768 + row2 + lane] = hprev;
}

// ---------------------------------------------------------------------------
// Final FC + sigmoid (unchanged)
// ---------------------------------------------------------------------------
__device__ __forceinline__ float dot4(float4 a, float4 b) {
    return a.x * b.x + a.y * b.y + a.z * b.z + a.w * b.w;
}

__global__ __launch_bounds__(64)
void fc_sig(const float* __restrict__ hin, const float* __restrict__ fw,
            const float* __restrict__ fb, float* __restrict__ out) {
    const int lane = threadIdx.x;
    const int row  = blockIdx.x;
    const float* wr = fw + (size_t)row * HC;
    float acc = 0.0f;
    #pragma unroll
    for (int i = 0; i < 6; ++i) {
        float4 w4 = *(const float4*)(wr  + i * 256 + lane * 4);
        float4 h4 = *(const float4*)(hin + i * 256 + lane * 4);
        acc += dot4(w4, h4);
    }
    #pragma unroll
    for (int s = 1; s < 64; s <<= 1) acc += __shfl_xor(acc, s);
    if (lane == 0) out[row] = sigf(acc + fb[row]);
}

// ---------------------------------------------------------------------------
extern "C" void kernel_launch(void* const* d_in, const int* in_sizes, int n_in,
                              void* d_out, int out_size, void* d_ws, size_t ws_size,
                              hipStream_t stream) {
    (void)in_sizes; (void)n_in; (void)out_size; (void)ws_size;

    const float* x     = (const float*)d_in[0];   // [8192,512]
    const float* h0    = (const float*)d_in[1];   // [4,768]
    const float* w_ih0 = (const float*)d_in[2];   // [2,2304,512]
    const float* w_hh0 = (const float*)d_in[3];   // [2,2304,768]
    const float* b_ih0 = (const float*)d_in[4];   // [2,2304]
    const float* b_hh0 = (const float*)d_in[5];
    const float* w_ih1 = (const float*)d_in[6];   // [2,2304,1536]
    const float* w_hh1 = (const float*)d_in[7];
    const float* b_ih1 = (const float*)d_in[8];
    const float* b_hh1 = (const float*)d_in[9];
    const float* fc_w  = (const float*)d_in[10];  // [256,1536]
    const float* fc_b  = (const float*)d_in[11];  // [256]
    float* out = (float*)d_out;

    char* ws = (char*)d_ws;
    // Exchange pair buffers (tags must start 0): 2*2*768*8 B = 24 KiB each.
    unsigned long long* exch0 = (unsigned long long*)(ws + 4096);
    unsigned long long* exch1 = (unsigned long long*)(ws + 4096 + 24576);
    float* Gi    = (float*)(ws + 65536);           // [8192][4608] fp32 = 144 MiB
    size_t gi_bytes = (size_t)T_STEPS * NDR * sizeof(float);
    float* Hout  = (float*)(ws + 65536 + gi_bytes); // [8192][2][768] = 48 MiB

    hipMemsetAsync(ws, 0, 65536, stream);

    dim3 ggrid(NDR / 128, T_STEPS / 128);  // (36, 64)

    // Phase 1: Gi0 = x @ w_ih0^T + b_ih0
    gemm_xwt<<<ggrid, 256, 0, stream>>>(x, w_ih0, b_ih0, Gi, T_STEPS, NDR, 512);
    // Phase 2: layer-0 recurrence, store all h0[t]
    gru_rec<<<NWG, 1024, 0, stream>>>(Gi, w_hh0, b_hh0, h0, exch0, Hout);
    // Phase 3: Gi1 = concat_h0 @ w_ih1^T + b_ih1
    gemm_xwt<<<ggrid, 256, 0, stream>>>(Hout, w_ih1, b_ih1, Gi, T_STEPS, NDR, HC);
    // Phase 4: layer-1 recurrence
    gru_rec<<<NWG, 1024, 0, stream>>>(Gi, w_hh1, b_hh1, h0 + 2 * HDIM, exch1, Hout);
    // Phase 5: y = sigmoid(fc_w @ h_last + fc_b)
    fc_sig<<<256, 64, 0, stream>>>(Hout + (size_t)(T_STEPS - 1) * HC,
                                   fc_w, fc_b, out);
}

// Round 6
// 54921.008 us; speedup vs baseline: 1.1545x; 1.1545x over previous
//
#include <hip/hip_runtime.h>
#include <cstdint>

#define T_STEPS 8192
#define HDIM    768
#define G3      2304   // 3*H
#define NDR     4608   // 2*3*H
#define HC      1536   // 2*H
#define GPD     96     // workgroups per direction
#define NWG     192    // 2 dirs x 96 WGs (independent cliques)
#define C_ROWS  8      // h-rows per workgroup (2 per wave)

// ---------------------------------------------------------------------------
// GEMM: C[m][n] = sum_k X[m][k] * W[n][k] + bias[n]  (unchanged)
// ---------------------------------------------------------------------------
__global__ __launch_bounds__(256)
void gemm_xwt(const float* __restrict__ X, const float* __restrict__ W,
              const float* __restrict__ bias, float* __restrict__ C,
              int M, int N, int K) {
    __shared__ float As[16][132];
    __shared__ float Bs[16][132];
    const int tid = threadIdx.x;
    const int m0 = blockIdx.y * 128;
    const int n0 = blockIdx.x * 128;
    const int tm = tid >> 4;
    const int tn = tid & 15;
    float acc[8][8] = {};
    for (int k0 = 0; k0 < K; k0 += 16) {
        #pragma unroll
        for (int l = 0; l < 2; ++l) {
            int idx = l * 256 + tid;
            int row = idx >> 2;
            int kc  = (idx & 3) << 2;
            float4 a = *(const float4*)(X + (size_t)(m0 + row) * K + k0 + kc);
            As[kc + 0][row] = a.x; As[kc + 1][row] = a.y;
            As[kc + 2][row] = a.z; As[kc + 3][row] = a.w;
            float4 b = *(const float4*)(W + (size_t)(n0 + row) * K + k0 + kc);
            Bs[kc + 0][row] = b.x; Bs[kc + 1][row] = b.y;
            Bs[kc + 2][row] = b.z; Bs[kc + 3][row] = b.w;
        }
        __syncthreads();
        #pragma unroll
        for (int k = 0; k < 16; ++k) {
            float4 a0 = *(const float4*)&As[k][tm * 8];
            float4 a1 = *(const float4*)&As[k][tm * 8 + 4];
            float4 b0 = *(const float4*)&Bs[k][tn * 8];
            float4 b1 = *(const float4*)&Bs[k][tn * 8 + 4];
            float av[8] = {a0.x, a0.y, a0.z, a0.w, a1.x, a1.y, a1.z, a1.w};
            float bv[8] = {b0.x, b0.y, b0.z, b0.w, b1.x, b1.y, b1.z, b1.w};
            #pragma unroll
            for (int i = 0; i < 8; ++i)
                #pragma unroll
                for (int j = 0; j < 8; ++j)
                    acc[i][j] = fmaf(av[i], bv[j], acc[i][j]);
        }
        __syncthreads();
    }
    float bfrag[8];
    #pragma unroll
    for (int j = 0; j < 8; ++j) bfrag[j] = bias[n0 + tn * 8 + j];
    #pragma unroll
    for (int i = 0; i < 8; ++i) {
        float* cp = C + (size_t)(m0 + tm * 8 + i) * N + n0 + tn * 8;
        float4 o0, o1;
        o0.x = acc[i][0] + bfrag[0]; o0.y = acc[i][1] + bfrag[1];
        o0.z = acc[i][2] + bfrag[2]; o0.w = acc[i][3] + bfrag[3];
        o1.x = acc[i][4] + bfrag[4]; o1.y = acc[i][5] + bfrag[5];
        o1.z = acc[i][6] + bfrag[6]; o1.w = acc[i][7] + bfrag[7];
        *(float4*)(cp + 0) = o0;
        *(float4*)(cp + 4) = o1;
    }
}

// ---------------------------------------------------------------------------
// GRU recurrence, R15 = R13's proven geometry (96 WGs/dir x 256 thr, 4 waves,
// 8 rows/WG) with ONE structural change: per-wave gates + single barrier.
// Each wave owns rows row2 = j0+2*wave, row2+1 (same per-lane dot partition
// and butterfly order as R13 -> bit-identical sums). After the butterfly,
// every lane holds all 6 sums, so lanes 0-1 compute their own rows' gates
// and publish immediately. Removed from the per-step chain: gsum LDS
// round-trip, barrier#2, and the cross-wave handoff to wave 0 (R13's
// phase 3). R14 already validated per-wave gates but confounded them with
// 16-wave WGs (fat barrier convoy, regressed); this keeps 4-wave WGs.
//
// Single-barrier safety: (i) intra-WG: wave A at step t+1 writes
// hsh[(t+1)&1] during its poll while a mate B still computing step t reads
// hsh[t&1] -- disjoint parity. A cannot pass poll(t+1) until B published
// step t (data dependence: poll waits on ALL rows incl. B's), and cannot
// reach step t+2's hsh[t&1] write before B passes barrier(t+1). (ii)
// cross-WG overwrite safety: producer P overwrites a parity slot holding
// tag t+1 at step t+2 only after P's poll(t+2) saw tags t+2 on all rows;
// each consumer C publishes tag t+2 only after C's barrier(t+1), which
// requires every C poll-thread to have read tag t+1 -- reads precede
// overwrite. Same induction as R9/R13.
// ---------------------------------------------------------------------------
__device__ __forceinline__ float sigf(float x) {
    return 1.0f / (1.0f + expf(-x));
}
__device__ __forceinline__ unsigned long long ld_pair(
        const unsigned long long* p) {
    return __hip_atomic_load(p, __ATOMIC_RELAXED, __HIP_MEMORY_SCOPE_AGENT);
}
__device__ __forceinline__ void st_pair(unsigned long long* p,
                                        unsigned long long v) {
    __hip_atomic_store(p, v, __ATOMIC_RELAXED, __HIP_MEMORY_SCOPE_AGENT);
}

__global__ __launch_bounds__(256, 1)
void gru_rec(const float* __restrict__ Gi,   // [T][2][2304]
             const float* __restrict__ whh,  // [2][2304][768]
             const float* __restrict__ bhh,  // [2][2304]
             const float* __restrict__ h0,   // [2][768] (layer slice)
             unsigned long long* __restrict__ exch, // [2 par][2 dir][768]
             float* __restrict__ Hout) {     // [T][2][768]
    const int tid  = threadIdx.x;
    const int lane = tid & 63;
    const int wave = tid >> 6;
    const int bid  = blockIdx.x;
    const int d    = bid / GPD;
    const int j0   = (bid % GPD) * C_ROWS;
    const int row2 = j0 + 2 * wave;          // first of this wave's two rows

    __shared__ float hsh[2][768];

    // Register-resident weights: m = g*2 + ri -> gate g, row = row2 + ri.
    // Per-lane coverage of h: elements i*256 + lane*4 .. +3 (same as R13).
    float4 w[6][3];
    #pragma unroll
    for (int g = 0; g < 3; ++g)
        #pragma unroll
        for (int ri = 0; ri < 2; ++ri) {
            const float* wrow = whh + (size_t)d * G3 * HDIM
                + (size_t)(g * 768 + row2 + ri) * HDIM;
            #pragma unroll
            for (int i = 0; i < 3; ++i)
                w[g * 2 + ri][i] = *(const float4*)(wrow + i * 256 + lane * 4);
        }

    // Gate lanes (lane 0-1 of each wave): row = row2 + lane.
    float bh_r = 0.f, bh_z = 0.f, bh_n = 0.f, hprev = 0.f;
    float gi_r = 0.f, gi_z = 0.f, gi_n = 0.f;
    if (lane < 2) {
        const int row = row2 + lane;
        bh_r  = bhh[d * G3 +        row];
        bh_z  = bhh[d * G3 +  768 + row];
        bh_n  = bhh[d * G3 + 1536 + row];
        hprev = h0[d * 768 + row];
        const float* gp = Gi + (size_t)d * G3;      // t = 0
        gi_r = gp[        row];
        gi_z = gp[ 768 + row];
        gi_n = gp[1536 + row];
    }

    for (int t = 0; t < T_STEPS; ++t) {
        // --- Phase 1: coalesced poll, 256 threads x 3 pairs (p = tid+256k) ---
        if (t == 0) {
            #pragma unroll
            for (int k = 0; k < 3; ++k)
                hsh[0][tid + 256 * k] = h0[d * 768 + tid + 256 * k];
        } else {
            const unsigned long long* src = exch
                + (size_t)((((t - 1) & 1) * 2 + d)) * 768 + tid;
            unsigned long long v[3];
            bool ok;
            do {
                #pragma unroll
                for (int k = 0; k < 3; ++k)
                    v[k] = ld_pair(src + 256 * k);
                ok = true;
                #pragma unroll
                for (int k = 0; k < 3; ++k)
                    ok &= ((unsigned)v[k] >= (unsigned)t);
            } while (!ok);
            #pragma unroll
            for (int k = 0; k < 3; ++k)
                hsh[t & 1][tid + 256 * k] =
                    __uint_as_float((unsigned)(v[k] >> 32));
        }
        __syncthreads();

        // --- Phase 2: deferred Hout(t-1) + Gi prefetch(t+1) (gate lanes) ---
        float ngr = 0.f, ngz = 0.f, ngn = 0.f;
        if (lane < 2) {
            const int row = row2 + lane;
            if (t > 0)
                Hout[((size_t)(t - 1) * 2 + d) * 768 + row] = hprev;
            if (t + 1 < T_STEPS) {
                const float* gp = Gi + ((size_t)(t + 1) * 2 + d) * G3;
                ngr = gp[        row];
                ngz = gp[ 768 + row];
                ngn = gp[1536 + row];
            }
        }

        // --- dots + butterfly (bit-identical arithmetic to R13) ---
        const float* hb = hsh[t & 1];
        float4 h4[3];
        #pragma unroll
        for (int i = 0; i < 3; ++i)
            h4[i] = *(const float4*)&hb[i * 256 + lane * 4];

        float S[6];
        #pragma unroll
        for (int m = 0; m < 6; ++m) {
            float s = 0.f;
            s = fmaf(w[m][0].x, h4[0].x, s); s = fmaf(w[m][0].y, h4[0].y, s);
            s = fmaf(w[m][0].z, h4[0].z, s); s = fmaf(w[m][0].w, h4[0].w, s);
            s = fmaf(w[m][1].x, h4[1].x, s); s = fmaf(w[m][1].y, h4[1].y, s);
            s = fmaf(w[m][1].z, h4[1].z, s); s = fmaf(w[m][1].w, h4[1].w, s);
            s = fmaf(w[m][2].x, h4[2].x, s); s = fmaf(w[m][2].y, h4[2].y, s);
            s = fmaf(w[m][2].z, h4[2].z, s); s = fmaf(w[m][2].w, h4[2].w, s);
            S[m] = s;
        }
        #pragma unroll
        for (int sft = 1; sft < 64; sft <<= 1) {
            #pragma unroll
            for (int m = 0; m < 6; ++m) S[m] += __shfl_xor(S[m], sft);
        }

        // --- Phase 3: per-wave gates + immediate publish (lanes 0-1) ---
        if (lane < 2) {
            float Sr = lane ? S[1] : S[0];
            float Sz = lane ? S[3] : S[2];
            float Sn = lane ? S[5] : S[4];
            float r = sigf(gi_r + Sr + bh_r);
            float z = sigf(gi_z + Sz + bh_z);
            float n = tanhf(gi_n + r * (Sn + bh_n));
            float hn = (1.0f - z) * n + z * hprev;
            hprev = hn;
            unsigned long long pair =
                ((unsigned long long)__float_as_uint(hn) << 32)
                | (unsigned long long)(unsigned)(t + 1);
            st_pair(exch + (size_t)(((t & 1) * 2 + d)) * 768 + row2 + lane,
                    pair);
            gi_r = ngr; gi_z = ngz; gi_n = ngn;
        }
        // single barrier per step: next iteration's poll barrier orders
        // everything; hsh parity covers the <=1-step intra-WG skew.
    }
    // flush the last Hout row
    if (lane < 2)
        Hout[((size_t)(T_STEPS - 1) * 2 + d) * 768 + row2 + lane] = hprev;
}

// ---------------------------------------------------------------------------
// Final FC + sigmoid (unchanged)
// ---------------------------------------------------------------------------
__device__ __forceinline__ float dot4(float4 a, float4 b) {
    return a.x * b.x + a.y * b.y + a.z * b.z + a.w * b.w;
}

__global__ __launch_bounds__(64)
void fc_sig(const float* __restrict__ hin, const float* __restrict__ fw,
            const float* __restrict__ fb, float* __restrict__ out) {
    const int lane = threadIdx.x;
    const int row  = blockIdx.x;
    const float* wr = fw + (size_t)row * HC;
    float acc = 0.0f;
    #pragma unroll
    for (int i = 0; i < 6; ++i) {
        float4 w4 = *(const float4*)(wr  + i * 256 + lane * 4);
        float4 h4 = *(const float4*)(hin + i * 256 + lane * 4);
        acc += dot4(w4, h4);
    }
    #pragma unroll
    for (int s = 1; s < 64; s <<= 1) acc += __shfl_xor(acc, s);
    if (lane == 0) out[row] = sigf(acc + fb[row]);
}

// ---------------------------------------------------------------------------
extern "C" void kernel_launch(void* const* d_in, const int* in_sizes, int n_in,
                              void* d_out, int out_size, void* d_ws, size_t ws_size,
                              hipStream_t stream) {
    (void)in_sizes; (void)n_in; (void)out_size; (void)ws_size;

    const float* x     = (const float*)d_in[0];   // [8192,512]
    const float* h0    = (const float*)d_in[1];   // [4,768]
    const float* w_ih0 = (const float*)d_in[2];   // [2,2304,512]
    const float* w_hh0 = (const float*)d_in[3];   // [2,2304,768]
    const float* b_ih0 = (const float*)d_in[4];   // [2,2304]
    const float* b_hh0 = (const float*)d_in[5];
    const float* w_ih1 = (const float*)d_in[6];   // [2,2304,1536]
    const float* w_hh1 = (const float*)d_in[7];
    const float* b_ih1 = (const float*)d_in[8];
    const float* b_hh1 = (const float*)d_in[9];
    const float* fc_w  = (const float*)d_in[10];  // [256,1536]
    const float* fc_b  = (const float*)d_in[11];  // [256]
    float* out = (float*)d_out;

    char* ws = (char*)d_ws;
    // Exchange pair buffers (tags must start 0): 2*2*768*8 B = 24 KiB each.
    unsigned long long* exch0 = (unsigned long long*)(ws + 4096);
    unsigned long long* exch1 = (unsigned long long*)(ws + 4096 + 24576);
    float* Gi    = (float*)(ws + 65536);           // [8192][4608] fp32 = 144 MiB
    size_t gi_bytes = (size_t)T_STEPS * NDR * sizeof(float);
    float* Hout  = (float*)(ws + 65536 + gi_bytes); // [8192][2][768] = 48 MiB

    hipMemsetAsync(ws, 0, 65536, stream);

    dim3 ggrid(NDR / 128, T_STEPS / 128);  // (36, 64)

    // Phase 1: Gi0 = x @ w_ih0^T + b_ih0
    gemm_xwt<<<ggrid, 256, 0, stream>>>(x, w_ih0, b_ih0, Gi, T_STEPS, NDR, 512);
    // Phase 2: layer-0 recurrence, store all h0[t]
    gru_rec<<<NWG, 256, 0, stream>>>(Gi, w_hh0, b_hh0, h0, exch0, Hout);
    // Phase 3: Gi1 = concat_h0 @ w_ih1^T + b_ih1
    gemm_xwt<<<ggrid, 256, 0, stream>>>(Hout, w_ih1, b_ih1, Gi, T_STEPS, NDR, HC);
    // Phase 4: layer-1 recurrence
    gru_rec<<<NWG, 256, 0, stream>>>(Gi, w_hh1, b_hh1, h0 + 2 * HDIM, exch1, Hout);
    // Phase 5: y = sigmoid(fc_w @ h_last + fc_b)
    fc_sig<<<256, 64, 0, stream>>>(Hout + (size_t)(T_STEPS - 1) * HC,
                                   fc_w, fc_b, out);
}

// Round 8
// 25060.857 us; speedup vs baseline: 2.5302x; 2.1915x over previous
//
#include <hip/hip_runtime.h>
#include <cstdint>

#define T_STEPS 8192
#define HDIM    768
#define G3      2304   // 3*H
#define NDR     4608   // 2*3*H
#define HC      1536   // 2*H
#define GPD     96     // rec workgroups per direction
#define C_ROWS  8      // h-rows per rec workgroup (2 per wave)
#define NL0     192
#define NL1     192
#define NG      64     // GEMM worker blocks
#define NWGF    (NL0 + NL1 + NG)   // 448 <= 512 co-resident slots
#define NTILES  (36 * 64)          // Gi1 tiles: 36 col-blocks x 64 row-blocks

// ---------------------------------------------------------------------------
// GEMM kernel (Phase 1 / Gi0 only). Tile arithmetic here is the numerics
// reference; the in-kernel worker below replicates it exactly.
// ---------------------------------------------------------------------------
__global__ __launch_bounds__(256)
void gemm_xwt(const float* __restrict__ X, const float* __restrict__ W,
              const float* __restrict__ bias, float* __restrict__ C,
              int M, int N, int K) {
    __shared__ float As[16][132];
    __shared__ float Bs[16][132];
    const int tid = threadIdx.x;
    const int m0 = blockIdx.y * 128;
    const int n0 = blockIdx.x * 128;
    const int tm = tid >> 4;
    const int tn = tid & 15;
    float acc[8][8] = {};
    for (int k0 = 0; k0 < K; k0 += 16) {
        #pragma unroll
        for (int l = 0; l < 2; ++l) {
            int idx = l * 256 + tid;
            int row = idx >> 2;
            int kc  = (idx & 3) << 2;
            float4 a = *(const float4*)(X + (size_t)(m0 + row) * K + k0 + kc);
            As[kc + 0][row] = a.x; As[kc + 1][row] = a.y;
            As[kc + 2][row] = a.z; As[kc + 3][row] = a.w;
            float4 b = *(const float4*)(W + (size_t)(n0 + row) * K + k0 + kc);
            Bs[kc + 0][row] = b.x; Bs[kc + 1][row] = b.y;
            Bs[kc + 2][row] = b.z; Bs[kc + 3][row] = b.w;
        }
        __syncthreads();
        #pragma unroll
        for (int k = 0; k < 16; ++k) {
            float4 a0 = *(const float4*)&As[k][tm * 8];
            float4 a1 = *(const float4*)&As[k][tm * 8 + 4];
            float4 b0 = *(const float4*)&Bs[k][tn * 8];
            float4 b1 = *(const float4*)&Bs[k][tn * 8 + 4];
            float av[8] = {a0.x, a0.y, a0.z, a0.w, a1.x, a1.y, a1.z, a1.w};
            float bv[8] = {b0.x, b0.y, b0.z, b0.w, b1.x, b1.y, b1.z, b1.w};
            #pragma unroll
            for (int i = 0; i < 8; ++i)
                #pragma unroll
                for (int j = 0; j < 8; ++j)
                    acc[i][j] = fmaf(av[i], bv[j], acc[i][j]);
        }
        __syncthreads();
    }
    float bfrag[8];
    #pragma unroll
    for (int j = 0; j < 8; ++j) bfrag[j] = bias[n0 + tn * 8 + j];
    #pragma unroll
    for (int i = 0; i < 8; ++i) {
        float* cp = C + (size_t)(m0 + tm * 8 + i) * N + n0 + tn * 8;
        float4 o0, o1;
        o0.x = acc[i][0] + bfrag[0]; o0.y = acc[i][1] + bfrag[1];
        o0.z = acc[i][2] + bfrag[2]; o0.w = acc[i][3] + bfrag[3];
        o1.x = acc[i][4] + bfrag[4]; o1.y = acc[i][5] + bfrag[5];
        o1.z = acc[i][6] + bfrag[6]; o1.w = acc[i][7] + bfrag[7];
        *(float4*)(cp + 0) = o0;
        *(float4*)(cp + 4) = o1;
    }
}

// ---------------------------------------------------------------------------
// R17 fused kernel: three roles, R13 bodies, DAG progress counters.
//  L0 (bid 0..191):  R13 layer-0 rec verbatim. Hout stores = agent-scope 4B
//    atomic stores (coherence-point visible, no dirty-L2 hazard). Every 64
//    steps: s_waitcnt vmcnt(0) then prog0[bid]=t (t rows complete).
//  Workers (bid 384..447): exact gemm_xwt tile arithmetic (bit-identical
//    Gi1 vs R13's GEMM3). Tile (mb,nb) gated on min(prog0)>=(mb+1)*128 +
//    acquire fence (invalidates stale L2 lines cross-XCD). Writes Gi1 IN
//    PLACE over Gi0 rows (safe: row r overwritten only after every L0 WG
//    passed step r, and L0 reads row r no later than its step r prefetch,
//    which precedes publishing prog>=r+1... precisely: prog>= (mb+1)*128
//    => all L0 finished step (mb+1)*128 => consumed rows <= (mb+1)*128;
//    worker writes rows < (mb+1)*128). Epilogue stores = agent atomics;
//    __syncthreads (drains all waves' stores) then tilecnt[mb] += 1.
//  L1 (bid 192..383): R13 layer-1 rec verbatim; at each 128-step boundary
//    waits tilecnt[rb]==36 + acquire fence, loads that step's Gi directly;
//    otherwise normal one-step prefetch (never crosses a boundary).
//  Deadlock-freedom under ANY dispatch order: __launch_bounds__(256,2)
//    => >=8 waves/CU => >=2 blocks/CU => all 448 blocks co-resident; the
//    wait graph L1 -> workers -> L0 -> (nothing) is acyclic; all spins on
//    fresh agent-scope atomics (R13-proven class, no guards needed).
//  Numerics: identical to R13 (proven absmax 0) in every stage.
// ---------------------------------------------------------------------------
__device__ __forceinline__ float sigf(float x) {
    return 1.0f / (1.0f + expf(-x));
}
__device__ __forceinline__ unsigned long long ld_pair(
        const unsigned long long* p) {
    return __hip_atomic_load(p, __ATOMIC_RELAXED, __HIP_MEMORY_SCOPE_AGENT);
}
__device__ __forceinline__ void st_pair(unsigned long long* p,
                                        unsigned long long v) {
    __hip_atomic_store(p, v, __ATOMIC_RELAXED, __HIP_MEMORY_SCOPE_AGENT);
}
__device__ __forceinline__ void st_f32(float* p, float v) {
    __hip_atomic_store(p, v, __ATOMIC_RELAXED, __HIP_MEMORY_SCOPE_AGENT);
}
__device__ __forceinline__ unsigned ld_u32(const unsigned* p) {
    return __hip_atomic_load(p, __ATOMIC_RELAXED, __HIP_MEMORY_SCOPE_AGENT);
}

__global__ __launch_bounds__(256, 2)
void gru_fused(float* Gi,                       // [T][2][2304]: Gi0 -> Gi1 in place
               const float* __restrict__ whh0,  // [2][2304][768]
               const float* __restrict__ bhh0,  // [2][2304]
               const float* __restrict__ wih1,  // [2][2304][1536]
               const float* __restrict__ bih1,  // [2][2304]
               const float* __restrict__ whh1,  // [2][2304][768]
               const float* __restrict__ bhh1,  // [2][2304]
               const float* __restrict__ h0g,   // [4][768]
               unsigned long long* exch0,       // [2][2][768] L0 clique
               unsigned long long* h1ex,        // [2][2][768] L1 clique
               unsigned* prog0,                 // [192]
               unsigned* tilecnt,               // [64]
               float* Hout,                     // [8192][1536]
               float* Hfin) {                   // [2][768]
    __shared__ __align__(16) char smem[16896];
    const int tid  = threadIdx.x;
    const int lane = tid & 63;
    const int wave = tid >> 6;
    const int bid  = blockIdx.x;

    if (bid < NL0 + NL1) {
        // ==================== recurrence roles (R13 body) ====================
        const bool isL0 = bid < NL0;
        const int rb = isL0 ? bid : bid - NL0;
        const int d  = rb / GPD;
        const int j0 = (rb % GPD) * C_ROWS;
        float (*hsh)[768] = (float (*)[768])smem;
        float* gsum = (float*)(smem + 6144);
        const float* whh = isL0 ? whh0 : whh1;
        const float* bhh = isL0 ? bhh0 : bhh1;
        unsigned long long* exch = isL0 ? exch0 : h1ex;
        const float* h0l = h0g + (isL0 ? 0 : 2) * 768;

        float4 w[6][3];
        #pragma unroll
        for (int g = 0; g < 3; ++g)
            #pragma unroll
            for (int ri = 0; ri < 2; ++ri) {
                const float* wrow = whh + (size_t)d * G3 * HDIM
                    + (size_t)(g * 768 + j0 + wave + 4 * ri) * HDIM;
                #pragma unroll
                for (int i = 0; i < 3; ++i)
                    w[g * 2 + ri][i] =
                        *(const float4*)(wrow + i * 256 + lane * 4);
            }

        float bh_r = 0.f, bh_z = 0.f, bh_n = 0.f, hprev = 0.f;
        float gi_r = 0.f, gi_z = 0.f, gi_n = 0.f;
        if (tid < 8) {
            const int row = j0 + tid;
            bh_r  = bhh[d * G3 +        row];
            bh_z  = bhh[d * G3 +  768 + row];
            bh_n  = bhh[d * G3 + 1536 + row];
            hprev = h0l[d * 768 + row];
            if (isL0) {               // L1 loads at its t=0 boundary instead
                const float* gp = Gi + (size_t)d * G3;
                gi_r = gp[        row];
                gi_z = gp[ 768 + row];
                gi_n = gp[1536 + row];
            }
        }

        for (int t = 0; t < T_STEPS; ++t) {
            // --- Phase 1: coalesced clique poll (pairs p = tid + 256k) ---
            if (t == 0) {
                #pragma unroll
                for (int k = 0; k < 3; ++k)
                    hsh[0][tid + 256 * k] = h0l[d * 768 + tid + 256 * k];
            } else {
                const unsigned long long* src = exch
                    + (size_t)((((t - 1) & 1) * 2 + d)) * 768 + tid;
                unsigned long long v[3];
                bool ok;
                do {
                    #pragma unroll
                    for (int k = 0; k < 3; ++k) v[k] = ld_pair(src + 256 * k);
                    ok = true;
                    #pragma unroll
                    for (int k = 0; k < 3; ++k)
                        ok &= ((unsigned)v[k] >= (unsigned)t);
                } while (!ok);
                #pragma unroll
                for (int k = 0; k < 3; ++k)
                    hsh[t & 1][tid + 256 * k] =
                        __uint_as_float((unsigned)(v[k] >> 32));
            }
            // L1: at a 128-row block boundary, wait for Gi1 tiles of this rb
            if (!isL0 && (t & 127) == 0) {
                if (tid == 0) {
                    while (ld_u32(&tilecnt[t >> 7]) < 36u)
                        __builtin_amdgcn_s_sleep(32);
                }
            }
            __syncthreads();
            if (!isL0 && (t & 127) == 0)
                __builtin_amdgcn_fence(__ATOMIC_ACQUIRE, "agent");

            // --- Phase 2: Hout(t-1) [L0], gi for step t [L1 boundary],
            //              gi prefetch(t+1), dots + butterfly ---
            float ngr = 0.f, ngz = 0.f, ngn = 0.f;
            if (tid < 8) {
                const int row = j0 + tid;
                if (isL0 && t > 0)
                    st_f32(Hout + (size_t)(t - 1) * HC + d * 768 + row, hprev);
                if (!isL0 && (t & 127) == 0) {   // direct load at boundary
                    const float* gp = Gi + ((size_t)t * 2 + d) * G3;
                    gi_r = gp[        row];
                    gi_z = gp[ 768 + row];
                    gi_n = gp[1536 + row];
                }
                if (t + 1 < T_STEPS && (isL0 || ((t + 1) & 127) != 0)) {
                    const float* gp = Gi + ((size_t)(t + 1) * 2 + d) * G3;
                    ngr = gp[        row];
                    ngz = gp[ 768 + row];
                    ngn = gp[1536 + row];
                }
            }

            const float* hb = hsh[t & 1];
            float4 h4[3];
            #pragma unroll
            for (int i = 0; i < 3; ++i)
                h4[i] = *(const float4*)&hb[i * 256 + lane * 4];
            float S[6];
            #pragma unroll
            for (int m = 0; m < 6; ++m) {
                float s = 0.f;
                s = fmaf(w[m][0].x, h4[0].x, s); s = fmaf(w[m][0].y, h4[0].y, s);
                s = fmaf(w[m][0].z, h4[0].z, s); s = fmaf(w[m][0].w, h4[0].w, s);
                s = fmaf(w[m][1].x, h4[1].x, s); s = fmaf(w[m][1].y, h4[1].y, s);
                s = fmaf(w[m][1].z, h4[1].z, s); s = fmaf(w[m][1].w, h4[1].w, s);
                s = fmaf(w[m][2].x, h4[2].x, s); s = fmaf(w[m][2].y, h4[2].y, s);
                s = fmaf(w[m][2].z, h4[2].z, s); s = fmaf(w[m][2].w, h4[2].w, s);
                S[m] = s;
            }
            #pragma unroll
            for (int sft = 1; sft < 64; sft <<= 1) {
                #pragma unroll
                for (int m = 0; m < 6; ++m) S[m] += __shfl_xor(S[m], sft);
            }
            if (lane < 6) gsum[wave * 6 + lane] = S[lane];
            __syncthreads();

            // --- Phase 3: gates + single 64-B publish (wave 0, tid<8) ---
            if (tid < 8) {
                const int wv = tid & 3, ri = tid >> 2;
                float Sr = gsum[wv * 6 + 0 + ri];
                float Sz = gsum[wv * 6 + 2 + ri];
                float Sn = gsum[wv * 6 + 4 + ri];
                float r = sigf(gi_r + Sr + bh_r);
                float z = sigf(gi_z + Sz + bh_z);
                float n = tanhf(gi_n + r * (Sn + bh_n));
                float hn = (1.0f - z) * n + z * hprev;
                hprev = hn;
                unsigned long long pair =
                    ((unsigned long long)__float_as_uint(hn) << 32)
                    | (unsigned long long)(unsigned)(t + 1);
                st_pair(exch + (size_t)(((t & 1) * 2 + d)) * 768 + j0 + tid,
                        pair);
                if (!isL0 && t == T_STEPS - 1)
                    Hfin[d * 768 + j0 + tid] = hn;
                gi_r = ngr; gi_z = ngz; gi_n = ngn;
            }
            if (isL0 && tid == 0 && t > 0 && (t & 63) == 0) {
                // rows 0..t-1 written (deferred store covered t-1 above);
                // drain Hout atomics, then publish progress = t.
                asm volatile("s_waitcnt vmcnt(0)" ::: "memory");
                __hip_atomic_store(&prog0[bid], (unsigned)t,
                                   __ATOMIC_RELAXED, __HIP_MEMORY_SCOPE_AGENT);
            }
        }
        if (isL0) {
            if (tid < 8)
                st_f32(Hout + (size_t)(T_STEPS - 1) * HC + d * 768 + j0 + tid,
                       hprev);
            if (tid == 0) {
                asm volatile("s_waitcnt vmcnt(0)" ::: "memory");
                __hip_atomic_store(&prog0[bid], (unsigned)T_STEPS,
                                   __ATOMIC_RELAXED, __HIP_MEMORY_SCOPE_AGENT);
            }
        }
    } else {
        // ==================== GEMM worker role ====================
        const int wkr = bid - (NL0 + NL1);
        float (*As)[132] = (float (*)[132])smem;
        float (*Bs)[132] = (float (*)[132])(smem + 8448);
        const int tm = tid >> 4;
        const int tn = tid & 15;
        for (int ti = wkr; ti < NTILES; ti += NG) {
            const int mb = ti / 36, nb = ti % 36;
            const int m0 = mb * 128, n0 = nb * 128;
            const unsigned need = (unsigned)((mb + 1) * 128);
            // gate: all 192 L0 WGs past row m0+127
            for (;;) {
                int myok = 1;
                if (tid < NL0) myok = (ld_u32(&prog0[tid]) >= need) ? 1 : 0;
                if (__syncthreads_and(myok)) break;
                __builtin_amdgcn_s_sleep(64);
            }
            __builtin_amdgcn_fence(__ATOMIC_ACQUIRE, "agent");
            // ---- exact gemm_xwt tile arithmetic (X=Hout, W=wih1, K=1536) ----
            float acc[8][8] = {};
            for (int k0 = 0; k0 < HC; k0 += 16) {
                #pragma unroll
                for (int l = 0; l < 2; ++l) {
                    int idx = l * 256 + tid;
                    int row = idx >> 2;
                    int kc  = (idx & 3) << 2;
                    float4 a = *(const float4*)(Hout
                        + (size_t)(m0 + row) * HC + k0 + kc);
                    As[kc + 0][row] = a.x; As[kc + 1][row] = a.y;
                    As[kc + 2][row] = a.z; As[kc + 3][row] = a.w;
                    float4 b = *(const float4*)(wih1
                        + (size_t)(n0 + row) * HC + k0 + kc);
                    Bs[kc + 0][row] = b.x; Bs[kc + 1][row] = b.y;
                    Bs[kc + 2][row] = b.z; Bs[kc + 3][row] = b.w;
                }
                __syncthreads();
                #pragma unroll
                for (int k = 0; k < 16; ++k) {
                    float4 a0 = *(const float4*)&As[k][tm * 8];
                    float4 a1 = *(const float4*)&As[k][tm * 8 + 4];
                    float4 b0 = *(const float4*)&Bs[k][tn * 8];
                    float4 b1 = *(const float4*)&Bs[k][tn * 8 + 4];
                    float av[8] = {a0.x, a0.y, a0.z, a0.w,
                                   a1.x, a1.y, a1.z, a1.w};
                    float bv[8] = {b0.x, b0.y, b0.z, b0.w,
                                   b1.x, b1.y, b1.z, b1.w};
                    #pragma unroll
                    for (int i = 0; i < 8; ++i)
                        #pragma unroll
                        for (int j = 0; j < 8; ++j)
                            acc[i][j] = fmaf(av[i], bv[j], acc[i][j]);
                }
                __syncthreads();
            }
            float bfrag[8];
            #pragma unroll
            for (int j = 0; j < 8; ++j) bfrag[j] = bih1[n0 + tn * 8 + j];
            #pragma unroll
            for (int i = 0; i < 8; ++i) {
                float* cp = Gi + (size_t)(m0 + tm * 8 + i) * NDR + n0 + tn * 8;
                #pragma unroll
                for (int j = 0; j < 8; ++j)
                    st_f32(cp + j, acc[i][j] + bfrag[j]);
            }
            __syncthreads();   // drains all waves' Gi stores (vmcnt(0))
            if (tid == 0)
                __hip_atomic_fetch_add(&tilecnt[mb], 1u,
                                       __ATOMIC_RELAXED,
                                       __HIP_MEMORY_SCOPE_AGENT);
        }
    }
}

// ---------------------------------------------------------------------------
// Final FC + sigmoid (unchanged; reads Hfin)
// ---------------------------------------------------------------------------
__device__ __forceinline__ float dot4(float4 a, float4 b) {
    return a.x * b.x + a.y * b.y + a.z * b.z + a.w * b.w;
}

__global__ __launch_bounds__(64)
void fc_sig(const float* __restrict__ hin, const float* __restrict__ fw,
            const float* __restrict__ fb, float* __restrict__ out) {
    const int lane = threadIdx.x;
    const int row  = blockIdx.x;
    const float* wr = fw + (size_t)row * HC;
    float acc = 0.0f;
    #pragma unroll
    for (int i = 0; i < 6; ++i) {
        float4 w4 = *(const float4*)(wr  + i * 256 + lane * 4);
        float4 h4 = *(const float4*)(hin + i * 256 + lane * 4);
        acc += dot4(w4, h4);
    }
    #pragma unroll
    for (int s = 1; s < 64; s <<= 1) acc += __shfl_xor(acc, s);
    if (lane == 0) out[row] = sigf(acc + fb[row]);
}

// ---------------------------------------------------------------------------
extern "C" void kernel_launch(void* const* d_in, const int* in_sizes, int n_in,
                              void* d_out, int out_size, void* d_ws, size_t ws_size,
                              hipStream_t stream) {
    (void)in_sizes; (void)n_in; (void)out_size; (void)ws_size;

    const float* x     = (const float*)d_in[0];   // [8192,512]
    const float* h0    = (const float*)d_in[1];   // [4,768]
    const float* w_ih0 = (const float*)d_in[2];   // [2,2304,512]
    const float* w_hh0 = (const float*)d_in[3];   // [2,2304,768]
    const float* b_ih0 = (const float*)d_in[4];   // [2,2304]
    const float* b_hh0 = (const float*)d_in[5];
    const float* w_ih1 = (const float*)d_in[6];   // [2,2304,1536]
    const float* w_hh1 = (const float*)d_in[7];
    const float* b_ih1 = (const float*)d_in[8];
    const float* b_hh1 = (const float*)d_in[9];
    const float* fc_w  = (const float*)d_in[10];  // [256,1536]
    const float* fc_b  = (const float*)d_in[11];  // [256]
    float* out = (float*)d_out;

    char* ws = (char*)d_ws;
    unsigned long long* exch0 = (unsigned long long*)(ws + 4096);   // 24576 B
    unsigned long long* h1ex  = (unsigned long long*)(ws + 28672);  // 24576 B
    unsigned* prog0   = (unsigned*)(ws + 53248);                    // 768 B
    unsigned* tilecnt = (unsigned*)(ws + 54016);                    // 256 B
    float* Hfin = (float*)(ws + 57344);                             // 6144 B
    float* Gi   = (float*)(ws + 65536);            // [8192][4608] = 144 MiB
    size_t gi_bytes = (size_t)T_STEPS * NDR * sizeof(float);
    float* Hout = (float*)(ws + 65536 + gi_bytes); // [8192][1536] = 48 MiB

    hipMemsetAsync(ws, 0, 65536, stream);

    dim3 ggrid(NDR / 128, T_STEPS / 128);  // (36, 64)

    // Phase 1: Gi0 = x @ w_ih0^T + b_ih0
    gemm_xwt<<<ggrid, 256, 0, stream>>>(x, w_ih0, b_ih0, Gi, T_STEPS, NDR, 512);
    // Phase 2: fused L0-rec || Gi1-GEMM || L1-rec pipeline
    gru_fused<<<NWGF, 256, 0, stream>>>(Gi, w_hh0, b_hh0,
                                        w_ih1, b_ih1, w_hh1, b_hh1,
                                        h0, exch0, h1ex, prog0, tilecnt,
                                        Hout, Hfin);
    // Phase 3: y = sigmoid(fc_w @ h1_last + fc_b)
    fc_sig<<<256, 64, 0, stream>>>(Hfin, fc_w, fc_b, out);
}